// Round 1
// baseline (694.467 us; speedup 1.0000x reference)
//
#include <hip/hip_runtime.h>
#include <hip/hip_bf16.h>

#define B_   32
#define NL   256
#define NH   16
#define DIN  16
#define DOUT 32
#define KK   8
#define DD   512            // Din*Dout
#define LC   8              // l-chunk size
#define NCHUNK (NL / LC)    // 32

// tmp2[l,h,i,o] = sum_k alpha[l,h,k] * W[k,i,o]
__global__ __launch_bounds__(512)
void tmp2_kernel(const float* __restrict__ W, const float* __restrict__ alpha,
                 float* __restrict__ tmp2) {
    const int lh = blockIdx.x;      // l*NH + h
    const int d  = threadIdx.x;     // 0..511 = i*32+o
    const float* a = alpha + lh * KK;
    float acc = 0.f;
#pragma unroll
    for (int k = 0; k < KK; ++k)
        acc = fmaf(a[k], W[k * DD + d], acc);
    tmp2[lh * DD + d] = acc;
}

// c[b,l,:] = softmax over Nh of blog[b,l,:]
__global__ __launch_bounds__(256)
void softmax_kernel(const float* __restrict__ blog, float* __restrict__ c) {
    const int tid = blockIdx.x * 256 + threadIdx.x;   // 0..8191 = b*NL+l
    float v[NH];
    const float4* src = (const float4*)(blog + tid * NH);
#pragma unroll
    for (int q = 0; q < 4; ++q) {
        float4 t = src[q];
        v[q*4+0] = t.x; v[q*4+1] = t.y; v[q*4+2] = t.z; v[q*4+3] = t.w;
    }
    float m = v[0];
#pragma unroll
    for (int j = 1; j < NH; ++j) m = fmaxf(m, v[j]);
    float s = 0.f;
#pragma unroll
    for (int j = 0; j < NH; ++j) { v[j] = expf(v[j] - m); s += v[j]; }
    const float inv = 1.0f / s;
    float4* dst = (float4*)(c + tid * NH);
#pragma unroll
    for (int q = 0; q < 4; ++q) {
        float4 t;
        t.x = v[q*4+0]*inv; t.y = v[q*4+1]*inv; t.z = v[q*4+2]*inv; t.w = v[q*4+3]*inv;
        dst[q] = t;
    }
}

// One block per (b,h). 256 threads.
// Phase 1: s[d] = sum_l c[b,l,h] * uhat[b,l,h,d]; squash -> v (LDS)
// Phase 2 (MODE 0/1): blog[b,l,h] (=|+=) dot(uhat[b,l,h,:], v)
// MODE 2: write v, a to output and stop after phase 1.
template <int MODE>
__global__ __launch_bounds__(256)
void route_kernel(const float* __restrict__ x, const float* __restrict__ tmp2,
                  const float* __restrict__ c_in, float* __restrict__ blog,
                  float* __restrict__ out_v, float* __restrict__ out_a) {
    __shared__ float xc[LC * 256];    // x[b, l0..l0+LC) : [lp][r*16+i]
    __shared__ float t2c[LC * DD];    // tmp2[l0+lp, h]  : [lp][i*32+o]
    __shared__ float v_lds[DD];
    __shared__ float cvals[LC];
    __shared__ float wsum[4];
    __shared__ float pred[4][LC];

    const int t = threadIdx.x;
    const int b = blockIdx.x >> 4;
    const int h = blockIdx.x & 15;

    // phase-1 mapping: thread t owns d = 2t, 2t+1  (same r, adjacent o)
    const int r  = t >> 4;            // (2t)>>5
    const int o0 = (2 * t) & 31;

    const float* xg  = x + (size_t)b * NL * 256;  // x[b] contiguous, 256 floats per l
    const float* t2g = tmp2 + h * DD;             // + l*NH*DD per row

    float s0 = 0.f, s1 = 0.f;

    for (int ch = 0; ch < NCHUNK; ++ch) {
        const int l0 = ch * LC;
        if (MODE != 0) {
            if (t < LC) cvals[t] = c_in[((size_t)b * NL + l0 + t) * NH + h];
        }
        // stage x chunk: LC*256 = 2048 floats = 512 float4
        {
            const float4* src = (const float4*)(xg + l0 * 256);
            float4* dst = (float4*)xc;
            dst[t]       = src[t];
            dst[t + 256] = src[t + 256];
        }
        // stage tmp2 chunk: LC*512 = 4096 floats = 1024 float4
        {
            float4* dst = (float4*)t2c;
#pragma unroll
            for (int rep = 0; rep < 4; ++rep) {
                const int e  = rep * 256 + t;   // 0..1023
                const int lp = e >> 7;
                const int j  = e & 127;
                dst[e] = ((const float4*)(t2g + (size_t)(l0 + lp) * NH * DD))[j];
            }
        }
        __syncthreads();
#pragma unroll
        for (int lp = 0; lp < LC; ++lp) {
            const float cv = (MODE == 0) ? (1.0f / 16.0f) : cvals[lp];
            const float* xr = &xc[lp * 256 + r * DIN];
            const float* t2 = &t2c[lp * DD];
            float u0 = 0.f, u1 = 0.f;
#pragma unroll
            for (int i = 0; i < DIN; ++i) {
                const float xv = xr[i];
                const float2 tv = *(const float2*)&t2[i * DOUT + o0];
                u0 = fmaf(xv, tv.x, u0);
                u1 = fmaf(xv, tv.y, u1);
            }
            s0 = fmaf(cv, u0, s0);
            s1 = fmaf(cv, u1, s1);
        }
        __syncthreads();
    }

    // squash: sq = sum_d s[d]^2 (block reduce)
    float sqp = s0 * s0 + s1 * s1;
#pragma unroll
    for (int m = 1; m < 64; m <<= 1) sqp += __shfl_xor(sqp, m, 64);
    if ((t & 63) == 0) wsum[t >> 6] = sqp;
    __syncthreads();
    const float sq    = wsum[0] + wsum[1] + wsum[2] + wsum[3];
    const float scale = sq / (1.0f + sq);
    const float inv   = scale / sqrtf(sq + 1e-11f);
    const float v0 = s0 * inv, v1 = s1 * inv;

    if (MODE == 2) {
        float2 vv; vv.x = v0; vv.y = v1;
        *(float2*)&out_v[((size_t)b * NH + h) * DD + 2 * t] = vv;
        if (t == 0) out_a[b * NH + h] = scale;
        return;
    }

    v_lds[2 * t]     = v0;
    v_lds[2 * t + 1] = v1;

    // phase 2: agreement dots. wave w covers d = w*128 + 2*lane + {0,1}
    const int wid  = t >> 6;
    const int lane = t & 63;
    const int d0   = wid * 128 + 2 * lane;
    const int r2   = d0 >> 5;
    const int o2   = d0 & 31;

    for (int ch = 0; ch < NCHUNK; ++ch) {
        const int l0 = ch * LC;
        {
            const float4* src = (const float4*)(xg + l0 * 256);
            float4* dst = (float4*)xc;
            dst[t]       = src[t];
            dst[t + 256] = src[t + 256];
        }
        {
            float4* dst = (float4*)t2c;
#pragma unroll
            for (int rep = 0; rep < 4; ++rep) {
                const int e  = rep * 256 + t;
                const int lp = e >> 7;
                const int j  = e & 127;
                dst[e] = ((const float4*)(t2g + (size_t)(l0 + lp) * NH * DD))[j];
            }
        }
        __syncthreads();   // staging done; also orders prev-chunk pred reads
        const float vd0 = v_lds[d0];
        const float vd1 = v_lds[d0 + 1];
#pragma unroll
        for (int lp = 0; lp < LC; ++lp) {
            const float* xr = &xc[lp * 256 + r2 * DIN];
            const float* t2 = &t2c[lp * DD];
            float u0 = 0.f, u1 = 0.f;
#pragma unroll
            for (int i = 0; i < DIN; ++i) {
                const float xv = xr[i];
                const float2 tv = *(const float2*)&t2[i * DOUT + o2];
                u0 = fmaf(xv, tv.x, u0);
                u1 = fmaf(xv, tv.y, u1);
            }
            float p = u0 * vd0 + u1 * vd1;
#pragma unroll
            for (int m = 1; m < 64; m <<= 1) p += __shfl_xor(p, m, 64);
            if (lane == 0) pred[wid][lp] = p;
        }
        __syncthreads();   // pred writes done
        if (t < LC) {
            const float dot = pred[0][t] + pred[1][t] + pred[2][t] + pred[3][t];
            const size_t idx = ((size_t)b * NL + l0 + t) * NH + h;
            if (MODE == 0) blog[idx] = dot;
            else           blog[idx] += dot;
        }
        // next chunk's staging only touches xc/t2c (read before 2nd sync);
        // next pred writes are after the next staging sync -> no race.
    }
}

extern "C" void kernel_launch(void* const* d_in, const int* in_sizes, int n_in,
                              void* d_out, int out_size, void* d_ws, size_t ws_size,
                              hipStream_t stream) {
    const float* x     = (const float*)d_in[0];
    // d_in[1] = adj (unused by forward)
    const float* W     = (const float*)d_in[2];
    const float* alpha = (const float*)d_in[3];
    float* out = (float*)d_out;

    float* ws   = (float*)d_ws;
    float* tmp2 = ws;                       // NL*NH*DD        = 2,097,152 floats
    float* blog = tmp2 + (size_t)NL * NH * DD;  // B*NL*NH     =   131,072
    float* cbuf = blog + (size_t)B_ * NL * NH;  // B*NL*NH     =   131,072

    float* out_v = out;                     // B*NH*DD = 262144
    float* out_a = out + (size_t)B_ * NH * DD;  // B*NH  =    512

    tmp2_kernel<<<NL * NH, 512, 0, stream>>>(W, alpha, tmp2);

    route_kernel<0><<<B_ * NH, 256, 0, stream>>>(x, tmp2, nullptr, blog, nullptr, nullptr);
    softmax_kernel<<<(B_ * NL) / 256, 256, 0, stream>>>(blog, cbuf);
    route_kernel<1><<<B_ * NH, 256, 0, stream>>>(x, tmp2, cbuf, blog, nullptr, nullptr);
    softmax_kernel<<<(B_ * NL) / 256, 256, 0, stream>>>(blog, cbuf);
    route_kernel<2><<<B_ * NH, 256, 0, stream>>>(x, tmp2, cbuf, blog, out_v, out_a);
}

// Round 5
// 439.275 us; speedup vs baseline: 1.5809x; 1.5809x over previous
//
#include <hip/hip_runtime.h>
#include <hip/hip_bf16.h>

#define B_     32
#define NL     256
#define NH     16
#define DIN    16
#define DOUT   32
#define KK     8
#define DD     512
#define LSPLIT 8
#define LPB    32          // l's per pass block

typedef __attribute__((ext_vector_type(8))) short sh8;
typedef __attribute__((ext_vector_type(4))) float f32x4;

__device__ __forceinline__ short f2b(float f) {   // fp32->bf16 RNE
    union { float f; unsigned u; } x; x.f = f;
    unsigned r = (x.u + 0x7FFFu + ((x.u >> 16) & 1u)) >> 16;
    return (short)r;
}
__device__ __forceinline__ float b2f(short s) {
    union { unsigned u; float f; } x; x.u = ((unsigned)(unsigned short)s) << 16;
    return x.f;
}
__device__ __forceinline__ void split3(float f, short& h, short& m, short& l) {
    h = f2b(f); float r1 = f - b2f(h);
    m = f2b(r1); float r2 = r1 - b2f(m);
    l = f2b(r2);
}

// 6-term product expansion: acc += (a0+a1+a2)*(b0+b1+b2) to ~2^-24
#define MFMA6(acc, a0, a1, a2, b0, b1, b2)                                    \
    acc = __builtin_amdgcn_mfma_f32_16x16x32_bf16(a0, b0, acc, 0, 0, 0);      \
    acc = __builtin_amdgcn_mfma_f32_16x16x32_bf16(a0, b1, acc, 0, 0, 0);      \
    acc = __builtin_amdgcn_mfma_f32_16x16x32_bf16(a1, b0, acc, 0, 0, 0);      \
    acc = __builtin_amdgcn_mfma_f32_16x16x32_bf16(a0, b2, acc, 0, 0, 0);      \
    acc = __builtin_amdgcn_mfma_f32_16x16x32_bf16(a1, b1, acc, 0, 0, 0);      \
    acc = __builtin_amdgcn_mfma_f32_16x16x32_bf16(a2, b0, acc, 0, 0, 0);

// tmp2[l,h,i,o] = sum_k alpha*W; store split3 TRANSPOSED [l,h][o*16+i]:
// hi|mid packed in uint, lo in short.
__global__ __launch_bounds__(512)
void tmp2_kernel(const float* __restrict__ W, const float* __restrict__ alpha,
                 unsigned int* __restrict__ t2hm, short* __restrict__ t2lo) {
    const int lh = blockIdx.x, d = threadIdx.x;
    const int i = d >> 5, o = d & 31;
    const float* a = alpha + lh * KK;
    float acc = 0.f;
#pragma unroll
    for (int k = 0; k < KK; ++k) acc = fmaf(a[k], W[k * DD + d], acc);
    short h, m, l; split3(acc, h, m, l);
    const size_t tt = (size_t)lh * DD + o * 16 + i;
    t2hm[tt] = ((unsigned int)(unsigned short)h << 16) | (unsigned short)m;
    t2lo[tt] = l;
}

// Deterministic fixed-order reduce of LSPLIT partials + squash.
// FIN=0: write v (fp32) to vbuf. FIN=1: write out_v/out_a.
template <int FIN>
__global__ __launch_bounds__(64)
void reduce_kernel(const float* __restrict__ spart, float* __restrict__ vbuf,
                   float* __restrict__ out_v, float* __restrict__ out_a) {
    const int bh = blockIdx.x, t = threadIdx.x;
    const int b = bh >> 4, h = bh & 15;
    float acc[8];
#pragma unroll
    for (int j = 0; j < 8; ++j) acc[j] = 0.f;
    for (int ls = 0; ls < LSPLIT; ++ls) {           // fixed order (determinism)
        const float* p = spart + (((size_t)(b * LSPLIT + ls) * NH + h) * DD) + t * 8;
        const float4 u0 = *(const float4*)&p[0];
        const float4 u1 = *(const float4*)&p[4];
        acc[0] += u0.x; acc[1] += u0.y; acc[2] += u0.z; acc[3] += u0.w;
        acc[4] += u1.x; acc[5] += u1.y; acc[6] += u1.z; acc[7] += u1.w;
    }
    float sq = 0.f;
#pragma unroll
    for (int j = 0; j < 8; ++j) sq = fmaf(acc[j], acc[j], sq);
#pragma unroll
    for (int mm = 1; mm < 64; mm <<= 1) sq += __shfl_xor(sq, mm, 64);
    const float scale = sq / (1.0f + sq);
    const float inv   = scale / sqrtf(sq + 1e-11f);
    if (FIN) {
        float* po = out_v + (size_t)bh * DD + t * 8;
#pragma unroll
        for (int j = 0; j < 8; ++j) po[j] = acc[j] * inv;
        if (t == 0) out_a[bh] = scale;
    } else {
        float* po = vbuf + (size_t)bh * DD + t * 8;
#pragma unroll
        for (int j = 0; j < 8; ++j) po[j] = acc[j] * inv;
    }
}

// One block per (b, l-chunk of 32). 512 thr = 8 waves; wave w handles h=2w,2w+1.
// Per l: uh = x . tmp2 via triple-split MFMA (K=32 padded, i<16);
// then dots (fp32), softmax (fp32), sacc += c*uh (fp32 regs, no atomics).
// MODE 0: c = 1/16, no dots. MODE 1: blog = dot. MODE 2: dot += blog.
template <int MODE>
__global__ __launch_bounds__(512)
void pass_kernel(const float* __restrict__ x,
                 const unsigned int* __restrict__ t2hm, const short* __restrict__ t2lo,
                 const float* __restrict__ vbuf, float* __restrict__ blog,
                 float* __restrict__ spart) {
    __shared__ __align__(16) float xc[LPB * 16 * 20];            // [l][r][20] 40KB
    __shared__ __align__(16) unsigned int thm[NH * 32 * 20];     // [h][o][20] 40KB
    __shared__ __align__(16) short tlo[NH * 32 * 24];            // [h][o][24] 24KB
    __shared__ float dotsL[16], cvals[16];

    const int t = threadIdx.x;
    const int b = blockIdx.x >> 3, ls = blockIdx.x & 7;
    const int l0 = ls * LPB;
    const int wv = t >> 6, lane = t & 63;
    const int lm = lane & 15, q = lane >> 4, qp = q & 1;

    // ---- stage x chunk (once): 32 l x 256 floats -> padded [l][r][20] ----
    const float4* xg = (const float4*)(x + ((size_t)b * NL + l0) * 256);
#pragma unroll
    for (int rep = 0; rep < 4; ++rep) {
        const int f4i = rep * 512 + t;          // 0..2047
        float4 v = xg[f4i];
        const int flat = f4i * 4;
        const int l = flat >> 8, rem = flat & 255;
        *(float4*)&xc[l * 320 + (rem >> 4) * 20 + (rem & 15)] = v;
    }

    // ---- v preload (fp32) ----
    float vr[2][2][4];
    if (MODE != 0) {
#pragma unroll
        for (int hh = 0; hh < 2; ++hh) {
            const float* vp = vbuf + ((size_t)b * NH + (wv * 2 + hh)) * DD;
#pragma unroll
            for (int blk = 0; blk < 2; ++blk)
#pragma unroll
                for (int reg = 0; reg < 4; ++reg)
                    vr[hh][blk][reg] = vp[(q * 4 + reg) * 32 + blk * 16 + lm];
        }
    }

    // ---- t2 prefetch regs ----
    uint4  pf_hm[4];
    float4 pf_lo[2];
    {
        const uint4*  sh = (const uint4*)(t2hm + (size_t)(l0) * NH * DD);
        const float4* sl = (const float4*)(t2lo + (size_t)(l0) * NH * DD);
#pragma unroll
        for (int rep = 0; rep < 4; ++rep) pf_hm[rep] = sh[rep * 512 + t];
#pragma unroll
        for (int rep = 0; rep < 2; ++rep) pf_lo[rep] = sl[rep * 512 + t];
    }

    float sacc[2][2][4];
#pragma unroll
    for (int a1 = 0; a1 < 2; ++a1)
#pragma unroll
        for (int a2 = 0; a2 < 2; ++a2)
#pragma unroll
            for (int a3 = 0; a3 < 4; ++a3) sacc[a1][a2][a3] = 0.f;

    for (int l = 0; l < LPB; ++l) {
        if (MODE == 0 && l > 0) __syncthreads();    // tc free (MODE!=0: barrier D covers)
        // write prefetched t2 slice to LDS (padded layouts)
#pragma unroll
        for (int rep = 0; rep < 4; ++rep) {
            const int f4i = rep * 512 + t;
            const int flat = f4i * 4;               // uint idx 0..8191
            const int h = flat >> 9, rem = flat & 511;
            *(uint4*)&thm[h * 640 + (rem >> 4) * 20 + (rem & 15)] = pf_hm[rep];
        }
#pragma unroll
        for (int rep = 0; rep < 2; ++rep) {
            const int f4i = rep * 512 + t;
            const int flat8 = f4i * 8;              // short idx 0..8191
            const int h = flat8 >> 9, rem = flat8 & 511;
            *(float4*)&tlo[h * 768 + (rem >> 4) * 24 + (rem & 15)] = pf_lo[rep];
        }
        if (l + 1 < LPB) {
            const uint4*  sh = (const uint4*)(t2hm + (size_t)(l0 + l + 1) * NH * DD);
            const float4* sl = (const float4*)(t2lo + (size_t)(l0 + l + 1) * NH * DD);
#pragma unroll
            for (int rep = 0; rep < 4; ++rep) pf_hm[rep] = sh[rep * 512 + t];
#pragma unroll
            for (int rep = 0; rep < 2; ++rep) pf_lo[rep] = sl[rep * 512 + t];
        }
        float blg = 0.f;
        if (MODE == 2 && t < 16) blg = blog[((size_t)b * NL + l0 + l) * NH + t];
        __syncthreads();                            // staging ready

        // ---- A-frags: x[l][r=lm][i=q*8+j], zero for q>=2 (K-pad) ----
        sh8 a0, a1, a2;
#pragma unroll
        for (int j = 0; j < 8; ++j) { a0[j] = 0; a1[j] = 0; a2[j] = 0; }
        if (q < 2) {
            const float* xr = &xc[l * 320 + lm * 20 + q * 8];
            float xv[8];
            *(float4*)&xv[0] = *(const float4*)&xr[0];
            *(float4*)&xv[4] = *(const float4*)&xr[4];
#pragma unroll
            for (int j = 0; j < 8; ++j) {
                short h_, m_, l_; split3(xv[j], h_, m_, l_);
                a0[j] = h_; a1[j] = m_; a2[j] = l_;
            }
        }

        // ---- per h: B-frags + MFMA6 -> P; dots ----
        f32x4 P[2][2];
#pragma unroll
        for (int hh = 0; hh < 2; ++hh) {
            const int h = wv * 2 + hh;
#pragma unroll
            for (int blk = 0; blk < 2; ++blk) {
                const unsigned int* hm = &thm[h * 640 + (blk * 16 + lm) * 20 + qp * 8];
                const uint4 u0 = *(const uint4*)&hm[0];
                const uint4 u1 = *(const uint4*)&hm[4];
                const sh8 b2v = *(const sh8*)&tlo[h * 768 + (blk * 16 + lm) * 24 + qp * 8];
                sh8 b0v, b1v;
                b0v[0] = (short)(u0.x >> 16); b1v[0] = (short)(u0.x & 0xFFFF);
                b0v[1] = (short)(u0.y >> 16); b1v[1] = (short)(u0.y & 0xFFFF);
                b0v[2] = (short)(u0.z >> 16); b1v[2] = (short)(u0.z & 0xFFFF);
                b0v[3] = (short)(u0.w >> 16); b1v[3] = (short)(u0.w & 0xFFFF);
                b0v[4] = (short)(u1.x >> 16); b1v[4] = (short)(u1.x & 0xFFFF);
                b0v[5] = (short)(u1.y >> 16); b1v[5] = (short)(u1.y & 0xFFFF);
                b0v[6] = (short)(u1.z >> 16); b1v[6] = (short)(u1.z & 0xFFFF);
                b0v[7] = (short)(u1.w >> 16); b1v[7] = (short)(u1.w & 0xFFFF);
                f32x4 acc = {0.f, 0.f, 0.f, 0.f};
                MFMA6(acc, a0, a1, a2, b0v, b1v, b2v)
                P[hh][blk] = acc;
            }
            if (MODE != 0) {
                float dp = 0.f;
#pragma unroll
                for (int blk = 0; blk < 2; ++blk)
#pragma unroll
                    for (int reg = 0; reg < 4; ++reg)
                        dp = fmaf(P[hh][blk][reg], vr[hh][blk][reg], dp);
#pragma unroll
                for (int mm = 1; mm < 64; mm <<= 1) dp += __shfl_xor(dp, mm, 64);
                if (lane == 0) dotsL[h] = dp;
            }
        }

        if (MODE != 0) {
            __syncthreads();                        // dotsL complete
            if (t < 16) {
                float d = dotsL[t];
                if (MODE == 1) blog[((size_t)b * NL + l0 + l) * NH + t] = d;
                else           d += blg;
                float mx = d;
#pragma unroll
                for (int mm = 1; mm < 16; mm <<= 1) mx = fmaxf(mx, __shfl_xor(mx, mm, 16));
                float e = expf(d - mx);
                float sum = e;
#pragma unroll
                for (int mm = 1; mm < 16; mm <<= 1) sum += __shfl_xor(sum, mm, 16);
                cvals[t] = e / sum;
            }
            __syncthreads();                        // cvals ready (also guards tc reuse)
        }

#pragma unroll
        for (int hh = 0; hh < 2; ++hh) {
            const float cv = (MODE == 0) ? (1.0f / 16.0f) : cvals[wv * 2 + hh];
#pragma unroll
            for (int blk = 0; blk < 2; ++blk)
#pragma unroll
                for (int reg = 0; reg < 4; ++reg)
                    sacc[hh][blk][reg] = fmaf(cv, P[hh][blk][reg], sacc[hh][blk][reg]);
        }
    }

    // ---- write s partials: d = r*32 + blk*16 + lm, r = q*4+reg ----
#pragma unroll
    for (int hh = 0; hh < 2; ++hh) {
        const int h = wv * 2 + hh;
        float* sp = spart + (((size_t)(b * LSPLIT + ls) * NH + h) * DD);
#pragma unroll
        for (int blk = 0; blk < 2; ++blk)
#pragma unroll
            for (int reg = 0; reg < 4; ++reg)
                sp[(q * 4 + reg) * 32 + blk * 16 + lm] = sacc[hh][blk][reg];
    }
}

extern "C" void kernel_launch(void* const* d_in, const int* in_sizes, int n_in,
                              void* d_out, int out_size, void* d_ws, size_t ws_size,
                              hipStream_t stream) {
    const float* x     = (const float*)d_in[0];
    // d_in[1] = adj (unused by forward)
    const float* W     = (const float*)d_in[2];
    const float* alpha = (const float*)d_in[3];
    float* out   = (float*)d_out;
    float* out_v = out;                          // B*NH*DD
    float* out_a = out + (size_t)B_ * NH * DD;   // B*NH

    char* w = (char*)d_ws;
    unsigned int* t2hm = (unsigned int*)w;  w += (size_t)2097152 * 4;  // 8 MB... no: 2M uints = 8MB? (2,097,152*4 = 8 MB) -- wait, 4 MB intended
    // NOTE: NL*NH*DD = 2,097,152 elements; uint plane = 8 MB is wrong — it's 4 bytes each => 8 MB.
    // Keep total modest: recompute offsets explicitly below instead.
    (void)w;
    char* base = (char*)d_ws;
    size_t off = 0;
    t2hm = (unsigned int*)(base + off); off += (size_t)NL * NH * DD * sizeof(unsigned int); // 8 MB
    short* t2lo = (short*)(base + off); off += (size_t)NL * NH * DD * sizeof(short);        // 4 MB
    float* spart = (float*)(base + off); off += (size_t)B_ * LSPLIT * NH * DD * sizeof(float); // 4 MB
    float* vbuf = (float*)(base + off); off += (size_t)B_ * NH * DD * sizeof(float);        // 1 MB
    float* blogp = (float*)(base + off); off += (size_t)B_ * NL * NH * sizeof(float);       // 0.5 MB

    tmp2_kernel<<<NL * NH, 512, 0, stream>>>(W, alpha, t2hm, t2lo);

    pass_kernel<0><<<B_ * LSPLIT, 512, 0, stream>>>(x, t2hm, t2lo, vbuf, blogp, spart);
    reduce_kernel<0><<<B_ * NH, 64, 0, stream>>>(spart, vbuf, nullptr, nullptr);

    pass_kernel<1><<<B_ * LSPLIT, 512, 0, stream>>>(x, t2hm, t2lo, vbuf, blogp, spart);
    reduce_kernel<0><<<B_ * NH, 64, 0, stream>>>(spart, vbuf, nullptr, nullptr);

    pass_kernel<2><<<B_ * LSPLIT, 512, 0, stream>>>(x, t2hm, t2lo, vbuf, blogp, spart);
    reduce_kernel<1><<<B_ * NH, 64, 0, stream>>>(spart, nullptr, out_v, out_a);
}

// Round 6
// 224.049 us; speedup vs baseline: 3.0996x; 1.9606x over previous
//
#include <hip/hip_runtime.h>
#include <hip/hip_bf16.h>

#define B_     32
#define NL     256
#define NH     16
#define DIN    16
#define DOUT   32
#define KK     8
#define DD     512
#define LPB    16          // l's per block
#define BG     2           // b's per block (packed into MFMA M)
#define PSTR   24          // xs LDS row stride in shorts (16 data + 8 pad, 16B-aligned)

typedef __attribute__((ext_vector_type(8)))  short sh8;
typedef __attribute__((ext_vector_type(16))) float f32x16;

__device__ __forceinline__ short f2b(float f) {   // fp32->bf16 RNE
    union { float f; unsigned u; } x; x.f = f;
    unsigned r = (x.u + 0x7FFFu + ((x.u >> 16) & 1u)) >> 16;
    return (short)r;
}
__device__ __forceinline__ float b2f(short s) {
    union { unsigned u; float f; } x; x.u = ((unsigned)(unsigned short)s) << 16;
    return x.f;
}
__device__ __forceinline__ void split3(float f, short& h, short& m, short& l) {
    h = f2b(f); float r1 = f - b2f(h);
    m = f2b(r1); float r2 = r1 - b2f(m);
    l = f2b(r2);
}

// acc += (a0+a1+a2)*(b0+b1+b2) to ~2^-24, 32x32x16
#define MFMA6_32(acc, a0, a1, a2, b0, b1, b2)                                  \
    acc = __builtin_amdgcn_mfma_f32_32x32x16_bf16(a0, b0, acc, 0, 0, 0);       \
    acc = __builtin_amdgcn_mfma_f32_32x32x16_bf16(a0, b1, acc, 0, 0, 0);       \
    acc = __builtin_amdgcn_mfma_f32_32x32x16_bf16(a1, b0, acc, 0, 0, 0);       \
    acc = __builtin_amdgcn_mfma_f32_32x32x16_bf16(a0, b2, acc, 0, 0, 0);       \
    acc = __builtin_amdgcn_mfma_f32_32x32x16_bf16(a1, b1, acc, 0, 0, 0);       \
    acc = __builtin_amdgcn_mfma_f32_32x32x16_bf16(a2, b0, acc, 0, 0, 0);

// tmp2[l,h,i,o] = sum_k alpha*W -> split3, transposed layout [l,h][o*16+i]
__global__ __launch_bounds__(512)
void tmp2_kernel(const float* __restrict__ W, const float* __restrict__ alpha,
                 short* __restrict__ p0, short* __restrict__ p1, short* __restrict__ p2) {
    const int lh = blockIdx.x, d = threadIdx.x;     // d = i*32+o
    const float* a = alpha + lh * KK;
    float acc = 0.f;
#pragma unroll
    for (int k = 0; k < KK; ++k) acc = fmaf(a[k], W[k * DD + d], acc);
    short h, m, l; split3(acc, h, m, l);
    const size_t tt = (size_t)lh * DD + (d & 31) * 16 + (d >> 5);
    p0[tt] = h; p1[tt] = m; p2[tt] = l;
}

// squash s -> v. MODE 0: scale 1/16 -> vbuf. MODE 1: -> vbuf. MODE 2: -> out.
template <int MODE>
__global__ __launch_bounds__(64)
void reduce_kernel(const float* __restrict__ s, float* __restrict__ vbuf,
                   float* __restrict__ out_v, float* __restrict__ out_a) {
    const int bh = blockIdx.x, t = threadIdx.x;
    const float cs = (MODE == 0) ? (1.0f / 16.0f) : 1.0f;
    const float* sp = s + (size_t)bh * DD + t * 8;
    float v[8];
#pragma unroll
    for (int j = 0; j < 8; ++j) v[j] = sp[j] * cs;
    float sq = 0.f;
#pragma unroll
    for (int j = 0; j < 8; ++j) sq = fmaf(v[j], v[j], sq);
#pragma unroll
    for (int mm = 1; mm < 64; mm <<= 1) sq += __shfl_xor(sq, mm, 64);
    const float scale = sq / (1.0f + sq);
    const float inv   = scale / sqrtf(sq + 1e-11f);
    float* po = (MODE == 2) ? (out_v + (size_t)bh * DD + t * 8)
                            : (vbuf + (size_t)bh * DD + t * 8);
#pragma unroll
    for (int j = 0; j < 8; ++j) po[j] = v[j] * inv;
    if (MODE == 2 && t == 0) out_a[bh] = scale;
}

// Block = (b-pair, l-chunk of 16). 512 thr = 8 waves; wave w owns h = 2w, 2w+1.
// Per (l,h): uh(2 b's, 16r, 32o) = one MFMA6 (32x32x16, M = b'*16+r, K = i).
// MODE 0: sacc += uh (c=1/16 in reduce). MODE 1: dots->blog=dot->softmax->sacc+=c*uh.
// MODE 2: dots, +blog, softmax, sacc+=c*uh.
template <int MODE>
__global__ __launch_bounds__(512)
void pass_kernel(const float* __restrict__ x,
                 const short* __restrict__ t0, const short* __restrict__ t1,
                 const short* __restrict__ t2p,
                 const float* __restrict__ vbuf, float* __restrict__ blog,
                 float* __restrict__ snext) {
    __shared__ __align__(16) short xs0[BG * LPB * 16 * PSTR];   // 24 KB each
    __shared__ __align__(16) short xs1[BG * LPB * 16 * PSTR];
    __shared__ __align__(16) short xs2[BG * LPB * 16 * PSTR];
    __shared__ float dotsL[2][16], cvals[2][16];

    const int t  = threadIdx.x;
    const int bg = blockIdx.x >> 4, lc = blockIdx.x & 15;  // blk%8 = lc%8 -> t2 L2 locality
    const int b0 = bg * BG, l0 = lc * LPB;
    const int wv = t >> 6, lane = t & 63;
    const int o  = lane & 31, l5 = lane >> 5;
    const int i0 = l5 * 8;

    // ---- stage x -> split3 padded LDS: xs[b'][l][r][PSTR] ----
#pragma unroll
    for (int rep = 0; rep < 2; ++rep) {
        const int idx = rep * 512 + t;              // 0..1023
        const int ih = idx & 1, r = (idx >> 1) & 15, p = idx >> 5;  // p = b'*16+l
        const float* xg = x + ((size_t)(b0 + (p >> 4)) * NL + l0 + (p & 15)) * 256
                            + r * 16 + ih * 8;
        float xv[8];
        *(float4*)&xv[0] = *(const float4*)&xg[0];
        *(float4*)&xv[4] = *(const float4*)&xg[4];
        sh8 v0, v1, v2;
#pragma unroll
        for (int j = 0; j < 8; ++j) {
            short h_, m_, l_; split3(xv[j], h_, m_, l_);
            v0[j] = h_; v1[j] = m_; v2[j] = l_;
        }
        const int la = (p * 16 + r) * PSTR + ih * 8;
        *(sh8*)&xs0[la] = v0; *(sh8*)&xs1[la] = v1; *(sh8*)&xs2[la] = v2;
    }
    __syncthreads();

    // ---- v preload (fp32 regs): vr[hh][b'][j], d = r(j,l5)*32 + o ----
    float vr[2][2][8];
    if (MODE != 0) {
#pragma unroll
        for (int hh = 0; hh < 2; ++hh) {
            const int h = wv * 2 + hh;
#pragma unroll
            for (int bq = 0; bq < 2; ++bq) {
                const float* vp = vbuf + ((size_t)(b0 + bq) * NH + h) * DD;
#pragma unroll
                for (int j = 0; j < 8; ++j) {
                    const int rr = (j & 3) + 8 * ((j >> 2) & 1) + 4 * l5;
                    vr[hh][bq][j] = vp[rr * 32 + o];
                }
            }
        }
    }

    f32x16 sacc[2];
#pragma unroll
    for (int hh = 0; hh < 2; ++hh)
#pragma unroll
        for (int j = 0; j < 16; ++j) sacc[hh][j] = 0.f;

    const int aoff0 = ((lane >> 4) & 1) * (LPB * 16 * PSTR) + (lane & 15) * PSTR + i0;

    for (int l = 0; l < LPB; ++l) {
        const int lg = l0 + l;
        const int ao = aoff0 + l * (16 * PSTR);
        const sh8 a0 = *(const sh8*)&xs0[ao];
        const sh8 a1 = *(const sh8*)&xs1[ao];
        const sh8 a2 = *(const sh8*)&xs2[ao];

        sh8 Bc[2][3];
        if (MODE != 0) {
#pragma unroll
            for (int hh = 0; hh < 2; ++hh) {
                const int h = wv * 2 + hh;
                const size_t tb = ((size_t)lg * NH + h) * DD + o * 16 + i0;
                Bc[hh][0] = *(const sh8*)(t0 + tb);
                Bc[hh][1] = *(const sh8*)(t1 + tb);
                Bc[hh][2] = *(const sh8*)(t2p + tb);
                f32x16 P;
#pragma unroll
                for (int j = 0; j < 16; ++j) P[j] = 0.f;
                MFMA6_32(P, a0, a1, a2, Bc[hh][0], Bc[hh][1], Bc[hh][2])
                float d0 = 0.f, d1 = 0.f;
#pragma unroll
                for (int j = 0; j < 8; ++j) d0 = fmaf(P[j], vr[hh][0][j], d0);
#pragma unroll
                for (int j = 0; j < 8; ++j) d1 = fmaf(P[8 + j], vr[hh][1][j], d1);
#pragma unroll
                for (int mm = 1; mm < 64; mm <<= 1) {
                    d0 += __shfl_xor(d0, mm, 64);
                    d1 += __shfl_xor(d1, mm, 64);
                }
                if (lane == 0) { dotsL[0][h] = d0; dotsL[1][h] = d1; }
            }
            __syncthreads();
            if (t < 32) {
                const int bq = t >> 4, h = t & 15;
                const size_t bi = ((size_t)(b0 + bq) * NL + lg) * NH;
                float vals[16];
#pragma unroll
                for (int hq = 0; hq < 16; ++hq) vals[hq] = dotsL[bq][hq];
                if (MODE == 1) {
                    blog[bi + h] = vals[h];
                } else {
#pragma unroll
                    for (int hq = 0; hq < 16; ++hq) vals[hq] += blog[bi + hq];
                }
                float mx = vals[0];
#pragma unroll
                for (int hq = 1; hq < 16; ++hq) mx = fmaxf(mx, vals[hq]);
                float sum = 0.f;
#pragma unroll
                for (int hq = 0; hq < 16; ++hq) sum += expf(vals[hq] - mx);
                cvals[bq][h] = expf(vals[h] - mx) / sum;
            }
            __syncthreads();
#pragma unroll
            for (int hh = 0; hh < 2; ++hh) {
                const int h = wv * 2 + hh;
                const float c0 = cvals[0][h], c1 = cvals[1][h];
                f32x16 P;
#pragma unroll
                for (int j = 0; j < 16; ++j) P[j] = 0.f;
                MFMA6_32(P, a0, a1, a2, Bc[hh][0], Bc[hh][1], Bc[hh][2])
#pragma unroll
                for (int j = 0; j < 8; ++j)  sacc[hh][j]     = fmaf(c0, P[j],     sacc[hh][j]);
#pragma unroll
                for (int j = 0; j < 8; ++j)  sacc[hh][8 + j] = fmaf(c1, P[8 + j], sacc[hh][8 + j]);
            }
        } else {
#pragma unroll
            for (int hh = 0; hh < 2; ++hh) {
                const int h = wv * 2 + hh;
                const size_t tb = ((size_t)lg * NH + h) * DD + o * 16 + i0;
                const sh8 b0f = *(const sh8*)(t0 + tb);
                const sh8 b1f = *(const sh8*)(t1 + tb);
                const sh8 b2f_ = *(const sh8*)(t2p + tb);
                MFMA6_32(sacc[hh], a0, a1, a2, b0f, b1f, b2f_)
            }
        }
    }

    // ---- epilogue: atomic accumulate s[b][h][d], d = r(j)*32 + o ----
#pragma unroll
    for (int hh = 0; hh < 2; ++hh) {
        const int h = wv * 2 + hh;
#pragma unroll
        for (int j = 0; j < 16; ++j) {
            const int bq = j >> 3;
            const int rr = (j & 3) + 8 * ((j >> 2) & 1) + 4 * l5;
            atomicAdd(&snext[((size_t)(b0 + bq) * NH + h) * DD + rr * 32 + o], sacc[hh][j]);
        }
    }
}

extern "C" void kernel_launch(void* const* d_in, const int* in_sizes, int n_in,
                              void* d_out, int out_size, void* d_ws, size_t ws_size,
                              hipStream_t stream) {
    const float* x     = (const float*)d_in[0];
    // d_in[1] = adj (unused by forward)
    const float* W     = (const float*)d_in[2];
    const float* alpha = (const float*)d_in[3];
    float* out   = (float*)d_out;
    float* out_v = out;                          // B*NH*DD
    float* out_a = out + (size_t)B_ * NH * DD;   // B*NH

    char* base = (char*)d_ws;
    size_t off = 0;
    short* t0   = (short*)(base + off); off += (size_t)NL * NH * DD * 2;   // 4 MB
    short* t1   = (short*)(base + off); off += (size_t)NL * NH * DD * 2;   // 4 MB
    short* t2p  = (short*)(base + off); off += (size_t)NL * NH * DD * 2;   // 4 MB
    float* s0   = (float*)(base + off); off += (size_t)B_ * NH * DD * 4;   // 1 MB
    float* s1   = (float*)(base + off); off += (size_t)B_ * NH * DD * 4;   // 1 MB
    float* vbuf = (float*)(base + off); off += (size_t)B_ * NH * DD * 4;   // 1 MB
    float* blogp= (float*)(base + off); off += (size_t)B_ * NL * NH * 4;   // 0.5 MB -> 15.5 MB

    hipMemsetAsync(s0, 0, (size_t)2 * B_ * NH * DD * 4, stream);   // s0 + s1

    tmp2_kernel<<<NL * NH, 512, 0, stream>>>(W, alpha, t0, t1, t2p);

    pass_kernel<0><<<(B_ / BG) * (NL / LPB), 512, 0, stream>>>(x, t0, t1, t2p, vbuf, blogp, s0);
    reduce_kernel<0><<<B_ * NH, 64, 0, stream>>>(s0, vbuf, nullptr, nullptr);

    pass_kernel<1><<<(B_ / BG) * (NL / LPB), 512, 0, stream>>>(x, t0, t1, t2p, vbuf, blogp, s1);
    reduce_kernel<1><<<B_ * NH, 64, 0, stream>>>(s1, vbuf, nullptr, nullptr);

    hipMemsetAsync(s0, 0, (size_t)B_ * NH * DD * 4, stream);       // reuse as s2

    pass_kernel<2><<<(B_ / BG) * (NL / LPB), 512, 0, stream>>>(x, t0, t1, t2p, vbuf, blogp, s0);
    reduce_kernel<2><<<B_ * NH, 64, 0, stream>>>(s0, nullptr, out_v, out_a);
}